// Round 7
// baseline (295.200 us; speedup 1.0000x reference)
//
#include <hip/hip_runtime.h>
#include <hip/hip_fp16.h>
#include <math.h>

#define FDIM  128
#define L1OUT 16
#define L2DIM 17
#define TRM   64      // f-rows per block (R6-proven: 128->64 took K1 out of the
                      // top-5; grid was occupancy-limiting at 3.05 blocks/CU)
#define HSTR  136     // LDS tile row stride in halves (272 B: 2-way-only conflicts)

typedef _Float16 f16x8 __attribute__((ext_vector_type(8)));   // MFMA A/B frag (4 VGPR)
typedef float    f32x4 __attribute__((ext_vector_type(4)));   // MFMA C/D frag

// one 32-byte fp16 node row (16 halves); align 16 -> 2x global_load_dwordx4
struct __align__(16) H16 { __half2 h[8]; };

__device__ __forceinline__ float lrelu(float v) { return v >= 0.f ? v : 0.1f * v; }

// ============================================================================
// K1 (MFMA, LDS-staged): [A|B] = f @ W'. TRM=64 (R6-proven).
// R4 lesson (permanent): cooperative grid.sync K2/K3 fusion pushed ssum
// traffic through HBM on non-coherent XCD L2s: 176us vs 58+12 split. Deleted.
// Layouts (HW-verified per guide): A-frag A[m=lane&15][k=(lane>>4)*8+j];
// B-frag B[k=(lane>>4)*8+j][n=lane&15]; C/D col=lane&15, row=(lane>>4)*4+reg.
// + degree atomics folded in (deg zeroed by memsetAsync before this kernel).
// ============================================================================
__global__ void node_transform(
    const float* __restrict__ f, const float* __restrict__ W1,
    const float* __restrict__ b1,
    const int* __restrict__ ind_i, const float* __restrict__ val,
    H16* __restrict__ A, H16* __restrict__ B,
    float* __restrict__ deg, int N, int E)
{
    __shared__ __align__(16) _Float16 tile[TRM * HSTR];   // 17.4 KB

    const int t    = threadIdx.x;
    const int gtid = blockIdx.x * 256 + t;
    const int GT   = gridDim.x * 256;

    // ---- degree atomics (grid-stride, fire-and-forget) ----
    {
        const int E4 = E >> 2;
        for (int q = gtid; q < E4; q += GT) {
            int e = q << 2;
            int4   ii = *reinterpret_cast<const int4*>(ind_i + e);
            float4 vv = *reinterpret_cast<const float4*>(val + e);
            atomicAdd(&deg[ii.x], fabsf(vv.x));
            atomicAdd(&deg[ii.y], fabsf(vv.y));
            atomicAdd(&deg[ii.z], fabsf(vv.z));
            atomicAdd(&deg[ii.w], fabsf(vv.w));
        }
        if (gtid < (E & 3)) {
            int e = (E & ~3) + gtid;
            atomicAdd(&deg[ind_i[e]], fabsf(val[e]));
        }
    }

    const int lane = t & 63;
    const int wv   = t >> 6;          // wave 0..3 -> M-subtile wv
    const int n    = lane & 15;       // MFMA matrix-dim index (col)
    const int quad = lane >> 4;       // k-block / row-group selector

    // ---- load W' B-frags once per block: bfr[nt][ks], k = 32*ks + 8*quad + j
    f16x8 bfr[2][4];
#pragma unroll
    for (int nt = 0; nt < 2; ++nt)
#pragma unroll
        for (int ks = 0; ks < 4; ++ks) {
            f16x8 bf;
#pragma unroll
            for (int j = 0; j < 8; ++j) {
                int k = 32 * ks + 8 * quad + j;
                bf[j] = (_Float16)W1[(size_t)(nt * FDIM + k) * L1OUT + n];
            }
            bfr[nt][ks] = bf;
        }
    float b1v = b1[n];                // folded into nt=0 accumulator init

    // ---- stage 64 f-rows as fp16 into padded LDS tile (coalesced) ----
    const int base = blockIdx.x * TRM;
#pragma unroll
    for (int q = 0; q < 4; ++q) {
        int p  = t + 256 * q;         // half8-chunk index 0..1023
        int r  = p >> 4;              // 16 chunks per row
        int c8 = p & 15;              // chunk within row (8 halves)
        float4 lo = make_float4(0.f, 0.f, 0.f, 0.f);
        float4 hi = lo;
        if (base + r < N) {
            const float4* src = reinterpret_cast<const float4*>(
                f + (size_t)(base + r) * FDIM + c8 * 8);
            lo = src[0];
            hi = src[1];
        }
        f16x8 hx;
        hx[0] = (_Float16)lo.x; hx[1] = (_Float16)lo.y;
        hx[2] = (_Float16)lo.z; hx[3] = (_Float16)lo.w;
        hx[4] = (_Float16)hi.x; hx[5] = (_Float16)hi.y;
        hx[6] = (_Float16)hi.z; hx[7] = (_Float16)hi.w;
        *reinterpret_cast<f16x8*>(&tile[r * HSTR + c8 * 8]) = hx;
    }
    __syncthreads();

    // ---- compute: wave wv handles M-subtile wv (16 rows) ----
    {
        const int m0 = wv * 16;
        f32x4 acc0 = { b1v, b1v, b1v, b1v };      // A-cols + b1
        f32x4 acc1 = { 0.f, 0.f, 0.f, 0.f };      // B-cols
#pragma unroll
        for (int ks = 0; ks < 4; ++ks) {
            // A-frag: row m0+n, k = 32*ks + 8*quad .. +7  (one ds_read_b128)
            f16x8 af = *reinterpret_cast<const f16x8*>(
                &tile[(m0 + n) * HSTR + 32 * ks + 8 * quad]);
            acc0 = __builtin_amdgcn_mfma_f32_16x16x32_f16(af, bfr[0][ks], acc0, 0, 0, 0);
            acc1 = __builtin_amdgcn_mfma_f32_16x16x32_f16(af, bfr[1][ks], acc1, 0, 0, 0);
        }
        // epilogue: D col = n, rows = m0 + quad*4 + reg
#pragma unroll
        for (int reg = 0; reg < 4; ++reg) {
            int node = base + m0 + quad * 4 + reg;
            if (node < N) {
                reinterpret_cast<_Float16*>(A + node)[n] = (_Float16)acc0[reg];
                reinterpret_cast<_Float16*>(B + node)[n] = (_Float16)acc1[reg];
            }
        }
    }
}

// ============================================================================
// Shared MLP tail: x[17] -> L2 layer -> collapse -> exp. NO references/structs
// in the hot path (R1 lesson: addressable gather results -> alloca -> 672 MB
// scratch traffic). All indices compile-time; SROA keeps everything in VGPRs.
// ============================================================================
#define MLP_TAIL(X, EXOUT)                                                  \
    {                                                                       \
        float acc[L2DIM];                                                   \
        _Pragma("unroll")                                                   \
        for (int r = 0; r < L2DIM; ++r) acc[r] = b2s[r];                    \
        _Pragma("unroll")                                                   \
        for (int c = 0; c < L2DIM; ++c) {                                   \
            float xc = X[c];                                                \
            const float4* r4 = reinterpret_cast<const float4*>(&w2s[c * 20]); \
            float4 w0 = r4[0], w1v = r4[1], w2v = r4[2], w3 = r4[3];        \
            float  w16 = w2s[c * 20 + 16];                                  \
            acc[0]  += xc * w0.x;  acc[1]  += xc * w0.y;                    \
            acc[2]  += xc * w0.z;  acc[3]  += xc * w0.w;                    \
            acc[4]  += xc * w1v.x; acc[5]  += xc * w1v.y;                   \
            acc[6]  += xc * w1v.z; acc[7]  += xc * w1v.w;                   \
            acc[8]  += xc * w2v.x; acc[9]  += xc * w2v.y;                   \
            acc[10] += xc * w2v.z; acc[11] += xc * w2v.w;                   \
            acc[12] += xc * w3.x;  acc[13] += xc * w3.y;                    \
            acc[14] += xc * w3.z;  acc[15] += xc * w3.w;                    \
            acc[16] += xc * w16;                                            \
        }                                                                   \
        float ev = bc0s;                                                    \
        _Pragma("unroll")                                                   \
        for (int r = 0; r < L2DIM; ++r) ev += lrelu(acc[r]) * wcs[r];       \
        EXOUT = __expf(ev);                                                 \
    }

#define EDGE_X(X, ALO, AHI, BLO, BHI, V, D)                                 \
    _Pragma("unroll")                                                       \
    for (int k = 0; k < 8; ++k) {                                           \
        X[k]     = lrelu((float)ALO[k] + (float)BLO[k]);                    \
        X[k + 8] = lrelu((float)AHI[k] + (float)BHI[k]);                    \
    }                                                                       \
    X[L1OUT] = fabsf(V) / D;

// ============================================================================
// K2: per-edge MLP -> exp -> segment-sum. TWO edges per thread (e, e+E/2).
// R5/R6 verdict: schedule-pinning (sched_barrier, asm liveness) produced ZERO
// delta twice -- per-thread ILP lever is dead; both pins removed.
// R7 insight: occupancy was capped by MY OWN __launch_bounds__(256,4) =
// 16 waves/CU = 50% hard cap (measured 30% incl. tail) -- set in R0 to allow
// 128 VGPRs the compiler never used (VGPR=64 every round). Now (256,8):
// 8 blocks/CU, 32 waves/CU possible, VGPR=64 is exactly the 8-wave boundary.
// REGIME TEST (pre-committed): dur -> ~40-48us = latency-bound confirmed;
// dur flat at ~58 with higher occupancy = random-access HBM roofline
// (A+B=6.4MB can't fit a 4MB XCD L2; 72MB of 64B-line gather misses) ->
// pivot to traffic reduction.
// R1 lesson: no references/structs/lambdas on gather results.
// Softmax max-pass removed: identical ratios; |e_val| <~ 15 (fp32-safe).
// ============================================================================
__global__ __launch_bounds__(256, 8) void edge_mlp(
    const int* __restrict__ ind, const float* __restrict__ val,
    const H16* __restrict__ A, const H16* __restrict__ B,
    const float* __restrict__ deg,
    const float* __restrict__ W2, const float* __restrict__ b2,
    const float* __restrict__ Wc, const float* __restrict__ bc,
    float* __restrict__ eout, float* __restrict__ ssum, int E)
{
    __shared__ float w2s[L2DIM * 20];   // row c at w2s[c*20], 16B-aligned
    __shared__ float b2s[L2DIM];
    __shared__ float wcs[L2DIM];
    __shared__ float bc0s;

    const int t = threadIdx.x;
    for (int idx = t; idx < L2DIM * L2DIM; idx += 256) {
        int c = idx / L2DIM, r = idx - c * L2DIM;
        w2s[c * 20 + r] = W2[idx];
    }
    if (t < L2DIM) b2s[t] = b2[t];
    if (t < L2DIM) wcs[t] = Wc[t];
    if (t == 0)    bc0s   = bc[0];
    __syncthreads();

    const int E2 = (E + 1) >> 1;          // pair stride
    const int p  = blockIdx.x * 256 + t;
    if (p >= E2) return;

    const int  e0   = p;
    const int  e1   = p + E2;
    const bool has1 = (e1 < E);
    const int  e1s  = has1 ? e1 : e0;     // safe clone address for tail

    // ---- issue the full load pipeline for both edges up front ----
    int i0 = ind[e0];   int j0 = ind[E + e0];
    int i1 = ind[e1s];  int j1 = ind[E + e1s];

    const f16x8* pA0 = reinterpret_cast<const f16x8*>(A + i0);
    const f16x8* pB0 = reinterpret_cast<const f16x8*>(B + j0);
    const f16x8* pA1 = reinterpret_cast<const f16x8*>(A + i1);
    const f16x8* pB1 = reinterpret_cast<const f16x8*>(B + j1);

    f16x8 a0lo = pA0[0], a0hi = pA0[1];   // 2x global_load_dwordx4 each
    f16x8 b0lo = pB0[0], b0hi = pB0[1];
    float v0   = val[e0];
    float d0   = deg[i0];
    f16x8 a1lo = pA1[0], a1hi = pA1[1];
    f16x8 b1lo = pB1[0], b1hi = pB1[1];
    float v1   = val[e1s];
    float d1   = deg[i1];

    // ---- edge 0 ----
    {
        float x[L2DIM];
        EDGE_X(x, a0lo, a0hi, b0lo, b0hi, v0, d0);
        float ex0;
        MLP_TAIL(x, ex0);
        eout[e0] = ex0;
        atomicAdd(&ssum[i0], ex0);
    }

    // ---- edge 1 ----
    if (has1) {
        float x[L2DIM];
        EDGE_X(x, a1lo, a1hi, b1lo, b1hi, v1, d1);
        float ex1;
        MLP_TAIL(x, ex1);
        eout[e1] = ex1;
        atomicAdd(&ssum[i1], ex1);
    }
}

// ============================================================================
// K3: out = ex / s[i], 4 edges/thread vectorized
// ============================================================================
__global__ void normalize(const int* __restrict__ ind_i, const float* __restrict__ ssum,
                          float* __restrict__ ex, int E) {
    int t = blockIdx.x * blockDim.x + threadIdx.x;
    int e = t * 4;
    if (e + 3 < E) {
        int4   ii = *reinterpret_cast<const int4*>(ind_i + e);
        float4 vv = *reinterpret_cast<const float4*>(ex + e);
        vv.x /= ssum[ii.x];
        vv.y /= ssum[ii.y];
        vv.z /= ssum[ii.z];
        vv.w /= ssum[ii.w];
        *reinterpret_cast<float4*>(ex + e) = vv;
    } else {
        for (; e < E; ++e) ex[e] = ex[e] / ssum[ind_i[e]];
    }
}

extern "C" void kernel_launch(void* const* d_in, const int* in_sizes, int n_in,
                              void* d_out, int out_size, void* d_ws, size_t ws_size,
                              hipStream_t stream) {
    const int*   Jt_ind = (const int*)  d_in[0];   // [2,E]
    const float* Jt_val = (const float*)d_in[1];   // [E]
    const float* f      = (const float*)d_in[2];   // [N,128]
    const float* W1 = (const float*)d_in[4];       // [256,16]
    const float* b1 = (const float*)d_in[5];       // [16]
    const float* W2 = (const float*)d_in[6];       // [17,17]
    const float* b2 = (const float*)d_in[7];       // [17]
    const float* Wc = (const float*)d_in[8];       // [17,1]
    const float* bc = (const float*)d_in[9];       // [1]

    const int E = in_sizes[1];
    const int N = in_sizes[2] / FDIM;
    float* out = (float*)d_out;                    // [E] fp32

    // workspace: deg[N] | ssum[N] (contiguous -> one memset) | A[N] | B[N]
    char* ws = (char*)d_ws;
    float* deg  = (float*)ws;  ws += (size_t)N * sizeof(float);
    float* ssum = (float*)ws;  ws += (size_t)N * sizeof(float);
    H16*   A    = (H16*)ws;    ws += (size_t)N * sizeof(H16);
    H16*   Bm   = (H16*)ws;    ws += (size_t)N * sizeof(H16);

    const int B256 = 256;
    const int nblk = (N + TRM - 1) / TRM;                   // node tiles (64 rows)
    const int E2   = (E + 1) / 2;                           // edge pairs
    const int eblk = (E2 + B256 - 1) / B256;                // 2 edges/thread
    const int qblk = ((E + 3) / 4 + B256 - 1) / B256;       // 4 edges/thread

    hipMemsetAsync(deg, 0, 2 * (size_t)N * sizeof(float), stream);
    node_transform<<<nblk, B256, 0, stream>>>(f, W1, b1, Jt_ind, Jt_val,
                                              A, Bm, deg, N, E);
    edge_mlp      <<<eblk, B256, 0, stream>>>(Jt_ind, Jt_val, A, Bm, deg,
                                              W2, b2, Wc, bc, out, ssum, E);
    normalize     <<<qblk, B256, 0, stream>>>(Jt_ind, ssum, out, E);
}

// Round 8
// 215.554 us; speedup vs baseline: 1.3695x; 1.3695x over previous
//
#include <hip/hip_runtime.h>
#include <hip/hip_fp16.h>
#include <math.h>

#define FDIM  128
#define L1OUT 16
#define L2DIM 17
#define TRM   192     // f-rows per block (R8: 768t, 12 waves x 16 rows; 521
                      // blocks -- dispatch-rate theory says FEWER, FATTER blocks)
#define HSTR  136     // LDS tile row stride in halves (272 B: 2-way-only conflicts)

typedef _Float16 f16x8 __attribute__((ext_vector_type(8)));   // MFMA A/B frag (4 VGPR)
typedef float    f32x4 __attribute__((ext_vector_type(4)));   // MFMA C/D frag

// one 32-byte fp16 node row (16 halves); align 16 -> 2x global_load_dwordx4
struct __align__(16) H16 { __half2 h[8]; };

__device__ __forceinline__ float lrelu(float v) { return v >= 0.f ? v : 0.1f * v; }

// ============================================================================
// K1 (MFMA, LDS-staged): [A|B] = f @ W'.
// R8 theory (from R7's accidental experiment): kernels with ~1500 short-lived
// blocks sit on a ~27 blocks/us dispatch-rate floor (K2: 1563 blk / 58.5us;
// R6's TRM=64 "fix" doubled K1's blocks to 1563 and the total stayed FLAT --
// block-latency halved but landed on the same dispatch floor). R7's spilled
// K2 (longer-lived blocks) saw occupancy 30->53% and HBM 2.1->3.3 TB/s with
// UNCHANGED resources -- residency builds when blocks live longer. Fix: fewer,
// fatter blocks. TRM=192 @ 768 threads: 12 waves x one 16-row subtile, LDS
// 52.2KB (3 blocks/CU), 521 blocks.
// R4 lesson (permanent): cooperative grid.sync K2/K3 fusion pushed ssum
// traffic through HBM on non-coherent XCD L2s: 176us vs 58+12 split. Deleted.
// Layouts (HW-verified per guide): A-frag A[m=lane&15][k=(lane>>4)*8+j];
// B-frag B[k=(lane>>4)*8+j][n=lane&15]; C/D col=lane&15, row=(lane>>4)*4+reg.
// + degree atomics folded in (deg zeroed by memsetAsync before this kernel).
// ============================================================================
__global__ void node_transform(
    const float* __restrict__ f, const float* __restrict__ W1,
    const float* __restrict__ b1,
    const int* __restrict__ ind_i, const float* __restrict__ val,
    H16* __restrict__ A, H16* __restrict__ B,
    float* __restrict__ deg, int N, int E)
{
    __shared__ __align__(16) _Float16 tile[TRM * HSTR];   // 52.2 KB

    const int t    = threadIdx.x;                          // 0..767
    const int gtid = blockIdx.x * 768 + t;
    const int GT   = gridDim.x * 768;

    // ---- degree atomics (grid-stride, fire-and-forget) ----
    {
        const int E4 = E >> 2;
        for (int q = gtid; q < E4; q += GT) {
            int e = q << 2;
            int4   ii = *reinterpret_cast<const int4*>(ind_i + e);
            float4 vv = *reinterpret_cast<const float4*>(val + e);
            atomicAdd(&deg[ii.x], fabsf(vv.x));
            atomicAdd(&deg[ii.y], fabsf(vv.y));
            atomicAdd(&deg[ii.z], fabsf(vv.z));
            atomicAdd(&deg[ii.w], fabsf(vv.w));
        }
        if (gtid < (E & 3)) {
            int e = (E & ~3) + gtid;
            atomicAdd(&deg[ind_i[e]], fabsf(val[e]));
        }
    }

    const int lane = t & 63;
    const int wv   = t >> 6;          // wave 0..11 -> M-subtile wv
    const int n    = lane & 15;       // MFMA matrix-dim index (col)
    const int quad = lane >> 4;       // k-block / row-group selector

    // ---- load W' B-frags once per block: bfr[nt][ks], k = 32*ks + 8*quad + j
    f16x8 bfr[2][4];
#pragma unroll
    for (int nt = 0; nt < 2; ++nt)
#pragma unroll
        for (int ks = 0; ks < 4; ++ks) {
            f16x8 bf;
#pragma unroll
            for (int j = 0; j < 8; ++j) {
                int k = 32 * ks + 8 * quad + j;
                bf[j] = (_Float16)W1[(size_t)(nt * FDIM + k) * L1OUT + n];
            }
            bfr[nt][ks] = bf;
        }
    float b1v = b1[n];                // folded into nt=0 accumulator init

    // ---- stage 192 f-rows as fp16 into padded LDS tile (coalesced) ----
    const int base = blockIdx.x * TRM;
#pragma unroll
    for (int q = 0; q < 4; ++q) {
        int p  = t + 768 * q;         // half8-chunk index 0..3071
        int r  = p >> 4;              // 16 chunks per row
        int c8 = p & 15;              // chunk within row (8 halves)
        float4 lo = make_float4(0.f, 0.f, 0.f, 0.f);
        float4 hi = lo;
        if (base + r < N) {
            const float4* src = reinterpret_cast<const float4*>(
                f + (size_t)(base + r) * FDIM + c8 * 8);
            lo = src[0];
            hi = src[1];
        }
        f16x8 hx;
        hx[0] = (_Float16)lo.x; hx[1] = (_Float16)lo.y;
        hx[2] = (_Float16)lo.z; hx[3] = (_Float16)lo.w;
        hx[4] = (_Float16)hi.x; hx[5] = (_Float16)hi.y;
        hx[6] = (_Float16)hi.z; hx[7] = (_Float16)hi.w;
        *reinterpret_cast<f16x8*>(&tile[r * HSTR + c8 * 8]) = hx;
    }
    __syncthreads();

    // ---- compute: wave wv handles M-subtile wv (16 rows) ----
    {
        const int m0 = wv * 16;
        f32x4 acc0 = { b1v, b1v, b1v, b1v };      // A-cols + b1
        f32x4 acc1 = { 0.f, 0.f, 0.f, 0.f };      // B-cols
#pragma unroll
        for (int ks = 0; ks < 4; ++ks) {
            // A-frag: row m0+n, k = 32*ks + 8*quad .. +7  (one ds_read_b128)
            f16x8 af = *reinterpret_cast<const f16x8*>(
                &tile[(m0 + n) * HSTR + 32 * ks + 8 * quad]);
            acc0 = __builtin_amdgcn_mfma_f32_16x16x32_f16(af, bfr[0][ks], acc0, 0, 0, 0);
            acc1 = __builtin_amdgcn_mfma_f32_16x16x32_f16(af, bfr[1][ks], acc1, 0, 0, 0);
        }
        // epilogue: D col = n, rows = m0 + quad*4 + reg
#pragma unroll
        for (int reg = 0; reg < 4; ++reg) {
            int node = base + m0 + quad * 4 + reg;
            if (node < N) {
                reinterpret_cast<_Float16*>(A + node)[n] = (_Float16)acc0[reg];
                reinterpret_cast<_Float16*>(B + node)[n] = (_Float16)acc1[reg];
            }
        }
    }
}

// ============================================================================
// Shared MLP tail: x[17] -> L2 layer -> collapse -> exp. NO references/structs
// in the hot path (R1 lesson: addressable gather results -> alloca -> 672 MB
// scratch traffic). All indices compile-time; SROA keeps everything in VGPRs.
// ============================================================================
#define MLP_TAIL(X, EXOUT)                                                  \
    {                                                                       \
        float acc[L2DIM];                                                   \
        _Pragma("unroll")                                                   \
        for (int r = 0; r < L2DIM; ++r) acc[r] = b2s[r];                    \
        _Pragma("unroll")                                                   \
        for (int c = 0; c < L2DIM; ++c) {                                   \
            float xc = X[c];                                                \
            const float4* r4 = reinterpret_cast<const float4*>(&w2s[c * 20]); \
            float4 w0 = r4[0], w1v = r4[1], w2v = r4[2], w3 = r4[3];        \
            float  w16 = w2s[c * 20 + 16];                                  \
            acc[0]  += xc * w0.x;  acc[1]  += xc * w0.y;                    \
            acc[2]  += xc * w0.z;  acc[3]  += xc * w0.w;                    \
            acc[4]  += xc * w1v.x; acc[5]  += xc * w1v.y;                   \
            acc[6]  += xc * w1v.z; acc[7]  += xc * w1v.w;                   \
            acc[8]  += xc * w2v.x; acc[9]  += xc * w2v.y;                   \
            acc[10] += xc * w2v.z; acc[11] += xc * w2v.w;                   \
            acc[12] += xc * w3.x;  acc[13] += xc * w3.y;                    \
            acc[14] += xc * w3.z;  acc[15] += xc * w3.w;                    \
            acc[16] += xc * w16;                                            \
        }                                                                   \
        float ev = bc0s;                                                    \
        _Pragma("unroll")                                                   \
        for (int r = 0; r < L2DIM; ++r) ev += lrelu(acc[r]) * wcs[r];       \
        EXOUT = __expf(ev);                                                 \
    }

#define EDGE_X(X, ALO, AHI, BLO, BHI, V, D)                                 \
    _Pragma("unroll")                                                       \
    for (int k = 0; k < 8; ++k) {                                           \
        X[k]     = lrelu((float)ALO[k] + (float)BLO[k]);                    \
        X[k + 8] = lrelu((float)AHI[k] + (float)BHI[k]);                    \
    }                                                                       \
    X[L1OUT] = fabsf(V) / D;

// ============================================================================
// K2: per-edge MLP -> exp -> segment-sum. TWO edges per thread (e, e+E/2),
// now in 1024-thread blocks -> 391 blocks (was 1563). R8 dispatch theory:
// the 58.5us floor across 4 different per-thread configs was the block FEED
// rate (~27 blk/us), not wave latency -- R7's spilled (long-lived) blocks saw
// occupancy 30->53% and HBM 3.3 TB/s. Per-thread code is byte-identical to
// the R2-proven version.
// R7 lesson: __launch_bounds__(256,8) made the allocator target 32 VGPR ->
// spill (228/246MB scratch). (1024) caps at 128; compiler naturally emits 64.
// R5/R6 verdict: ILP schedule-pinning is dead (zero delta twice, removed).
// R1 lesson: no references/structs/lambdas on gather results.
// Softmax max-pass removed: identical ratios; |e_val| <~ 15 (fp32-safe).
// ============================================================================
__global__ __launch_bounds__(1024) void edge_mlp(
    const int* __restrict__ ind, const float* __restrict__ val,
    const H16* __restrict__ A, const H16* __restrict__ B,
    const float* __restrict__ deg,
    const float* __restrict__ W2, const float* __restrict__ b2,
    const float* __restrict__ Wc, const float* __restrict__ bc,
    float* __restrict__ eout, float* __restrict__ ssum, int E)
{
    __shared__ float w2s[L2DIM * 20];   // row c at w2s[c*20], 16B-aligned
    __shared__ float b2s[L2DIM];
    __shared__ float wcs[L2DIM];
    __shared__ float bc0s;

    const int t = threadIdx.x;
    if (t < L2DIM * L2DIM) {
        int c = t / L2DIM, r = t - c * L2DIM;
        w2s[c * 20 + r] = W2[t];
    }
    if (t < L2DIM) b2s[t] = b2[t];
    if (t < L2DIM) wcs[t] = Wc[t];
    if (t == 0)    bc0s   = bc[0];
    __syncthreads();

    const int E2 = (E + 1) >> 1;          // pair stride
    const int p  = blockIdx.x * 1024 + t;
    if (p >= E2) return;

    const int  e0   = p;
    const int  e1   = p + E2;
    const bool has1 = (e1 < E);
    const int  e1s  = has1 ? e1 : e0;     // safe clone address for tail

    // ---- issue the full load pipeline for both edges up front ----
    int i0 = ind[e0];   int j0 = ind[E + e0];
    int i1 = ind[e1s];  int j1 = ind[E + e1s];

    const f16x8* pA0 = reinterpret_cast<const f16x8*>(A + i0);
    const f16x8* pB0 = reinterpret_cast<const f16x8*>(B + j0);
    const f16x8* pA1 = reinterpret_cast<const f16x8*>(A + i1);
    const f16x8* pB1 = reinterpret_cast<const f16x8*>(B + j1);

    f16x8 a0lo = pA0[0], a0hi = pA0[1];   // 2x global_load_dwordx4 each
    f16x8 b0lo = pB0[0], b0hi = pB0[1];
    float v0   = val[e0];
    float d0   = deg[i0];
    f16x8 a1lo = pA1[0], a1hi = pA1[1];
    f16x8 b1lo = pB1[0], b1hi = pB1[1];
    float v1   = val[e1s];
    float d1   = deg[i1];

    // ---- edge 0 ----
    {
        float x[L2DIM];
        EDGE_X(x, a0lo, a0hi, b0lo, b0hi, v0, d0);
        float ex0;
        MLP_TAIL(x, ex0);
        eout[e0] = ex0;
        atomicAdd(&ssum[i0], ex0);
    }

    // ---- edge 1 ----
    if (has1) {
        float x[L2DIM];
        EDGE_X(x, a1lo, a1hi, b1lo, b1hi, v1, d1);
        float ex1;
        MLP_TAIL(x, ex1);
        eout[e1] = ex1;
        atomicAdd(&ssum[i1], ex1);
    }
}

// ============================================================================
// K3: out = ex / s[i], 4 edges/thread vectorized, 1024-thread blocks (196 blk)
// ============================================================================
__global__ __launch_bounds__(1024) void normalize(
    const int* __restrict__ ind_i, const float* __restrict__ ssum,
    float* __restrict__ ex, int E) {
    int t = blockIdx.x * blockDim.x + threadIdx.x;
    int e = t * 4;
    if (e + 3 < E) {
        int4   ii = *reinterpret_cast<const int4*>(ind_i + e);
        float4 vv = *reinterpret_cast<const float4*>(ex + e);
        vv.x /= ssum[ii.x];
        vv.y /= ssum[ii.y];
        vv.z /= ssum[ii.z];
        vv.w /= ssum[ii.w];
        *reinterpret_cast<float4*>(ex + e) = vv;
    } else {
        for (; e < E; ++e) ex[e] = ex[e] / ssum[ind_i[e]];
    }
}

extern "C" void kernel_launch(void* const* d_in, const int* in_sizes, int n_in,
                              void* d_out, int out_size, void* d_ws, size_t ws_size,
                              hipStream_t stream) {
    const int*   Jt_ind = (const int*)  d_in[0];   // [2,E]
    const float* Jt_val = (const float*)d_in[1];   // [E]
    const float* f      = (const float*)d_in[2];   // [N,128]
    const float* W1 = (const float*)d_in[4];       // [256,16]
    const float* b1 = (const float*)d_in[5];       // [16]
    const float* W2 = (const float*)d_in[6];       // [17,17]
    const float* b2 = (const float*)d_in[7];       // [17]
    const float* Wc = (const float*)d_in[8];       // [17,1]
    const float* bc = (const float*)d_in[9];       // [1]

    const int E = in_sizes[1];
    const int N = in_sizes[2] / FDIM;
    float* out = (float*)d_out;                    // [E] fp32

    // workspace: deg[N] | ssum[N] (contiguous -> one memset) | A[N] | B[N]
    char* ws = (char*)d_ws;
    float* deg  = (float*)ws;  ws += (size_t)N * sizeof(float);
    float* ssum = (float*)ws;  ws += (size_t)N * sizeof(float);
    H16*   A    = (H16*)ws;    ws += (size_t)N * sizeof(H16);
    H16*   Bm   = (H16*)ws;    ws += (size_t)N * sizeof(H16);

    const int nblk = (N + TRM - 1) / TRM;                   // 521 node tiles
    const int E2   = (E + 1) / 2;                           // edge pairs
    const int eblk = (E2 + 1023) / 1024;                    // 391 blocks
    const int qblk = ((E + 3) / 4 + 1023) / 1024;           // 196 blocks

    hipMemsetAsync(deg, 0, 2 * (size_t)N * sizeof(float), stream);
    node_transform<<<nblk, 768,  0, stream>>>(f, W1, b1, Jt_ind, Jt_val,
                                              A, Bm, deg, N, E);
    edge_mlp      <<<eblk, 1024, 0, stream>>>(Jt_ind, Jt_val, A, Bm, deg,
                                              W2, b2, Wc, bc, out, ssum, E);
    normalize     <<<qblk, 1024, 0, stream>>>(Jt_ind, ssum, out, E);
}

// Round 9
// 214.623 us; speedup vs baseline: 1.3754x; 1.0043x over previous
//
#include <hip/hip_runtime.h>
#include <hip/hip_fp16.h>
#include <math.h>

#define FDIM  128
#define L1OUT 16
#define L2DIM 17
#define TRM   192     // f-rows per block in node_transform (768t, 12 waves)
#define HSTR  136     // LDS tile row stride in halves (272 B: 2-way-only conflicts)

typedef _Float16 f16x8 __attribute__((ext_vector_type(8)));   // MFMA A/B frag (4 VGPR)
typedef float    f32x4 __attribute__((ext_vector_type(4)));   // MFMA C/D frag

// one 32-byte fp16 node row (16 halves); align 16 -> 2x global_load_dwordx4
struct __align__(16) H16 { __half2 h[8]; };

__device__ __forceinline__ float lrelu(float v) { return v >= 0.f ? v : 0.1f * v; }

// ============================================================================
// K0 (R9 EXPERIMENT): degree atomics ONLY, split out of node_transform.
// Theory under test: 800k device-scope atomicAdds saturate per-CU vmem
// trackers (each atomic holds a slot for its full coherence round-trip),
// starving co-resident loads -- unifying why K1 and K2 BOTH sit at ~59us with
// 800k atomics each, VALUBusy 2.4%/22%, flat across 5 geometry configs
// (R0/R2/R5/R6/R8) and immune to ILP pinning (R5/R6 nulls).
// Pre-committed read: dur ~8-15us => interference (loads were the victims;
// keep split, R10 separates K2's atomics). dur ~45-55us => chip-wide atomic
// floor (R10: privatized shard accumulators).
// ============================================================================
__global__ __launch_bounds__(256) void degree_pass(
    const int* __restrict__ ind_i, const float* __restrict__ val,
    float* __restrict__ deg, int E)
{
    const int gtid = blockIdx.x * 256 + threadIdx.x;
    const int GT   = gridDim.x * 256;
    const int E4   = E >> 2;
    for (int q = gtid; q < E4; q += GT) {
        int e = q << 2;
        int4   ii = *reinterpret_cast<const int4*>(ind_i + e);
        float4 vv = *reinterpret_cast<const float4*>(val + e);
        atomicAdd(&deg[ii.x], fabsf(vv.x));
        atomicAdd(&deg[ii.y], fabsf(vv.y));
        atomicAdd(&deg[ii.z], fabsf(vv.z));
        atomicAdd(&deg[ii.w], fabsf(vv.w));
    }
    if (gtid < (E & 3)) {
        int e = (E & ~3) + gtid;
        atomicAdd(&deg[ind_i[e]], fabsf(val[e]));
    }
}

// ============================================================================
// K1 (MFMA, LDS-staged, ATOMIC-FREE): [A|B] = f @ W'. TRM=192 @ 768 threads.
// With the degree pass removed this is pure stream+MFMA: 12.8MB ind/val gone,
// 51MB f read (L3-resident) + 6.4MB A/B write. Streaming bound ~15-25us.
// R4 lesson (permanent): cooperative grid.sync K2/K3 fusion pushed ssum
// traffic through HBM on non-coherent XCD L2s: 176us vs 58+12 split. Deleted.
// Layouts (HW-verified per guide): A-frag A[m=lane&15][k=(lane>>4)*8+j];
// B-frag B[k=(lane>>4)*8+j][n=lane&15]; C/D col=lane&15, row=(lane>>4)*4+reg.
// ============================================================================
__global__ void node_transform(
    const float* __restrict__ f, const float* __restrict__ W1,
    const float* __restrict__ b1,
    H16* __restrict__ A, H16* __restrict__ B, int N)
{
    __shared__ __align__(16) _Float16 tile[TRM * HSTR];   // 52.2 KB

    const int t    = threadIdx.x;                          // 0..767
    const int lane = t & 63;
    const int wv   = t >> 6;          // wave 0..11 -> M-subtile wv
    const int n    = lane & 15;       // MFMA matrix-dim index (col)
    const int quad = lane >> 4;       // k-block / row-group selector

    // ---- load W' B-frags once per block: bfr[nt][ks], k = 32*ks + 8*quad + j
    f16x8 bfr[2][4];
#pragma unroll
    for (int nt = 0; nt < 2; ++nt)
#pragma unroll
        for (int ks = 0; ks < 4; ++ks) {
            f16x8 bf;
#pragma unroll
            for (int j = 0; j < 8; ++j) {
                int k = 32 * ks + 8 * quad + j;
                bf[j] = (_Float16)W1[(size_t)(nt * FDIM + k) * L1OUT + n];
            }
            bfr[nt][ks] = bf;
        }
    float b1v = b1[n];                // folded into nt=0 accumulator init

    // ---- stage 192 f-rows as fp16 into padded LDS tile (coalesced) ----
    const int base = blockIdx.x * TRM;
#pragma unroll
    for (int q = 0; q < 4; ++q) {
        int p  = t + 768 * q;         // half8-chunk index 0..3071
        int r  = p >> 4;              // 16 chunks per row
        int c8 = p & 15;              // chunk within row (8 halves)
        float4 lo = make_float4(0.f, 0.f, 0.f, 0.f);
        float4 hi = lo;
        if (base + r < N) {
            const float4* src = reinterpret_cast<const float4*>(
                f + (size_t)(base + r) * FDIM + c8 * 8);
            lo = src[0];
            hi = src[1];
        }
        f16x8 hx;
        hx[0] = (_Float16)lo.x; hx[1] = (_Float16)lo.y;
        hx[2] = (_Float16)lo.z; hx[3] = (_Float16)lo.w;
        hx[4] = (_Float16)hi.x; hx[5] = (_Float16)hi.y;
        hx[6] = (_Float16)hi.z; hx[7] = (_Float16)hi.w;
        *reinterpret_cast<f16x8*>(&tile[r * HSTR + c8 * 8]) = hx;
    }
    __syncthreads();

    // ---- compute: wave wv handles M-subtile wv (16 rows) ----
    {
        const int m0 = wv * 16;
        f32x4 acc0 = { b1v, b1v, b1v, b1v };      // A-cols + b1
        f32x4 acc1 = { 0.f, 0.f, 0.f, 0.f };      // B-cols
#pragma unroll
        for (int ks = 0; ks < 4; ++ks) {
            // A-frag: row m0+n, k = 32*ks + 8*quad .. +7  (one ds_read_b128)
            f16x8 af = *reinterpret_cast<const f16x8*>(
                &tile[(m0 + n) * HSTR + 32 * ks + 8 * quad]);
            acc0 = __builtin_amdgcn_mfma_f32_16x16x32_f16(af, bfr[0][ks], acc0, 0, 0, 0);
            acc1 = __builtin_amdgcn_mfma_f32_16x16x32_f16(af, bfr[1][ks], acc1, 0, 0, 0);
        }
        // epilogue: D col = n, rows = m0 + quad*4 + reg
#pragma unroll
        for (int reg = 0; reg < 4; ++reg) {
            int node = base + m0 + quad * 4 + reg;
            if (node < N) {
                reinterpret_cast<_Float16*>(A + node)[n] = (_Float16)acc0[reg];
                reinterpret_cast<_Float16*>(B + node)[n] = (_Float16)acc1[reg];
            }
        }
    }
}

// ============================================================================
// Shared MLP tail: x[17] -> L2 layer -> collapse -> exp. NO references/structs
// in the hot path (R1 lesson: addressable gather results -> alloca -> 672 MB
// scratch traffic). All indices compile-time; SROA keeps everything in VGPRs.
// ============================================================================
#define MLP_TAIL(X, EXOUT)                                                  \
    {                                                                       \
        float acc[L2DIM];                                                   \
        _Pragma("unroll")                                                   \
        for (int r = 0; r < L2DIM; ++r) acc[r] = b2s[r];                    \
        _Pragma("unroll")                                                   \
        for (int c = 0; c < L2DIM; ++c) {                                   \
            float xc = X[c];                                                \
            const float4* r4 = reinterpret_cast<const float4*>(&w2s[c * 20]); \
            float4 w0 = r4[0], w1v = r4[1], w2v = r4[2], w3 = r4[3];        \
            float  w16 = w2s[c * 20 + 16];                                  \
            acc[0]  += xc * w0.x;  acc[1]  += xc * w0.y;                    \
            acc[2]  += xc * w0.z;  acc[3]  += xc * w0.w;                    \
            acc[4]  += xc * w1v.x; acc[5]  += xc * w1v.y;                   \
            acc[6]  += xc * w1v.z; acc[7]  += xc * w1v.w;                   \
            acc[8]  += xc * w2v.x; acc[9]  += xc * w2v.y;                   \
            acc[10] += xc * w2v.z; acc[11] += xc * w2v.w;                   \
            acc[12] += xc * w3.x;  acc[13] += xc * w3.y;                    \
            acc[14] += xc * w3.z;  acc[15] += xc * w3.w;                    \
            acc[16] += xc * w16;                                            \
        }                                                                   \
        float ev = bc0s;                                                    \
        _Pragma("unroll")                                                   \
        for (int r = 0; r < L2DIM; ++r) ev += lrelu(acc[r]) * wcs[r];       \
        EXOUT = __expf(ev);                                                 \
    }

#define EDGE_X(X, ALO, AHI, BLO, BHI, V, D)                                 \
    _Pragma("unroll")                                                       \
    for (int k = 0; k < 8; ++k) {                                           \
        X[k]     = lrelu((float)ALO[k] + (float)BLO[k]);                    \
        X[k + 8] = lrelu((float)AHI[k] + (float)BHI[k]);                    \
    }                                                                       \
    X[L1OUT] = fabsf(V) / D;

// ============================================================================
// K2: per-edge MLP -> exp -> segment-sum. R2-exact configuration (best
// measured: 58.2us): 256 threads, 2 edges/thread (e, e+E/2), lb(256,4).
// Geometry exhausted (R0/R2/R5/R6/R8 all 58-63us); R8 refuted dispatch-rate.
// R7 lesson: lb(256,8) -> 32-VGPR target -> spill. R5/R6: ILP pins are dead.
// R1 lesson: no references/structs/lambdas on gather results.
// Softmax max-pass removed: identical ratios; |e_val| <~ 15 (fp32-safe).
// ============================================================================
__global__ __launch_bounds__(256, 4) void edge_mlp(
    const int* __restrict__ ind, const float* __restrict__ val,
    const H16* __restrict__ A, const H16* __restrict__ B,
    const float* __restrict__ deg,
    const float* __restrict__ W2, const float* __restrict__ b2,
    const float* __restrict__ Wc, const float* __restrict__ bc,
    float* __restrict__ eout, float* __restrict__ ssum, int E)
{
    __shared__ float w2s[L2DIM * 20];   // row c at w2s[c*20], 16B-aligned
    __shared__ float b2s[L2DIM];
    __shared__ float wcs[L2DIM];
    __shared__ float bc0s;

    const int t = threadIdx.x;
    for (int idx = t; idx < L2DIM * L2DIM; idx += 256) {
        int c = idx / L2DIM, r = idx - c * L2DIM;
        w2s[c * 20 + r] = W2[idx];
    }
    if (t < L2DIM) b2s[t] = b2[t];
    if (t < L2DIM) wcs[t] = Wc[t];
    if (t == 0)    bc0s   = bc[0];
    __syncthreads();

    const int E2 = (E + 1) >> 1;          // pair stride
    const int p  = blockIdx.x * 256 + t;
    if (p >= E2) return;

    const int  e0   = p;
    const int  e1   = p + E2;
    const bool has1 = (e1 < E);
    const int  e1s  = has1 ? e1 : e0;     // safe clone address for tail

    // ---- issue the full load pipeline for both edges up front ----
    int i0 = ind[e0];   int j0 = ind[E + e0];
    int i1 = ind[e1s];  int j1 = ind[E + e1s];

    const f16x8* pA0 = reinterpret_cast<const f16x8*>(A + i0);
    const f16x8* pB0 = reinterpret_cast<const f16x8*>(B + j0);
    const f16x8* pA1 = reinterpret_cast<const f16x8*>(A + i1);
    const f16x8* pB1 = reinterpret_cast<const f16x8*>(B + j1);

    f16x8 a0lo = pA0[0], a0hi = pA0[1];   // 2x global_load_dwordx4 each
    f16x8 b0lo = pB0[0], b0hi = pB0[1];
    float v0   = val[e0];
    float d0   = deg[i0];
    f16x8 a1lo = pA1[0], a1hi = pA1[1];
    f16x8 b1lo = pB1[0], b1hi = pB1[1];
    float v1   = val[e1s];
    float d1   = deg[i1];

    // ---- edge 0 ----
    {
        float x[L2DIM];
        EDGE_X(x, a0lo, a0hi, b0lo, b0hi, v0, d0);
        float ex0;
        MLP_TAIL(x, ex0);
        eout[e0] = ex0;
        atomicAdd(&ssum[i0], ex0);
    }

    // ---- edge 1 ----
    if (has1) {
        float x[L2DIM];
        EDGE_X(x, a1lo, a1hi, b1lo, b1hi, v1, d1);
        float ex1;
        MLP_TAIL(x, ex1);
        eout[e1] = ex1;
        atomicAdd(&ssum[i1], ex1);
    }
}

// ============================================================================
// K3: out = ex / s[i], 4 edges/thread vectorized (R2-proven)
// ============================================================================
__global__ void normalize(const int* __restrict__ ind_i, const float* __restrict__ ssum,
                          float* __restrict__ ex, int E) {
    int t = blockIdx.x * blockDim.x + threadIdx.x;
    int e = t * 4;
    if (e + 3 < E) {
        int4   ii = *reinterpret_cast<const int4*>(ind_i + e);
        float4 vv = *reinterpret_cast<const float4*>(ex + e);
        vv.x /= ssum[ii.x];
        vv.y /= ssum[ii.y];
        vv.z /= ssum[ii.z];
        vv.w /= ssum[ii.w];
        *reinterpret_cast<float4*>(ex + e) = vv;
    } else {
        for (; e < E; ++e) ex[e] = ex[e] / ssum[ind_i[e]];
    }
}

extern "C" void kernel_launch(void* const* d_in, const int* in_sizes, int n_in,
                              void* d_out, int out_size, void* d_ws, size_t ws_size,
                              hipStream_t stream) {
    const int*   Jt_ind = (const int*)  d_in[0];   // [2,E]
    const float* Jt_val = (const float*)d_in[1];   // [E]
    const float* f      = (const float*)d_in[2];   // [N,128]
    const float* W1 = (const float*)d_in[4];       // [256,16]
    const float* b1 = (const float*)d_in[5];       // [16]
    const float* W2 = (const float*)d_in[6];       // [17,17]
    const float* b2 = (const float*)d_in[7];       // [17]
    const float* Wc = (const float*)d_in[8];       // [17,1]
    const float* bc = (const float*)d_in[9];       // [1]

    const int E = in_sizes[1];
    const int N = in_sizes[2] / FDIM;
    float* out = (float*)d_out;                    // [E] fp32

    // workspace: deg[N] | ssum[N] (contiguous -> one memset) | A[N] | B[N]
    char* ws = (char*)d_ws;
    float* deg  = (float*)ws;  ws += (size_t)N * sizeof(float);
    float* ssum = (float*)ws;  ws += (size_t)N * sizeof(float);
    H16*   A    = (H16*)ws;    ws += (size_t)N * sizeof(H16);
    H16*   Bm   = (H16*)ws;    ws += (size_t)N * sizeof(H16);

    const int B256 = 256;
    const int dblk = ((E + 3) / 4 + B256 - 1) / B256;       // degree pass
    const int nblk = (N + TRM - 1) / TRM;                   // 521 node tiles
    const int E2   = (E + 1) / 2;                           // edge pairs
    const int eblk = (E2 + B256 - 1) / B256;                // 1563 blocks (R2)
    const int qblk = ((E + 3) / 4 + B256 - 1) / B256;       // 782 blocks

    hipMemsetAsync(deg, 0, 2 * (size_t)N * sizeof(float), stream);
    degree_pass   <<<dblk, B256, 0, stream>>>(Jt_ind, Jt_val, deg, E);
    node_transform<<<nblk, 768,  0, stream>>>(f, W1, b1, A, Bm, N);
    edge_mlp      <<<eblk, B256, 0, stream>>>(Jt_ind, Jt_val, A, Bm, deg,
                                              W2, b2, Wc, bc, out, ssum, E);
    normalize     <<<qblk, B256, 0, stream>>>(Jt_ind, ssum, out, E);
}

// Round 10
// 207.138 us; speedup vs baseline: 1.4251x; 1.0361x over previous
//
#include <hip/hip_runtime.h>
#include <hip/hip_fp16.h>
#include <math.h>

#define FDIM  128
#define L1OUT 16
#define L2DIM 17
#define TRM   64      // f-rows per block (R6-proven geometry; also restores the
                      // exact A/B writer layout edge_mlp was fastest under)
#define HSTR  136     // LDS tile row stride in halves (272 B: 2-way-only conflicts)

typedef _Float16 f16x8 __attribute__((ext_vector_type(8)));   // MFMA A/B frag (4 VGPR)
typedef float    f32x4 __attribute__((ext_vector_type(4)));   // MFMA C/D frag

// one 32-byte fp16 node row (16 halves); align 16 -> 2x global_load_dwordx4
struct __align__(16) H16 { __half2 h[8]; };

__device__ __forceinline__ float lrelu(float v) { return v >= 0.f ? v : 0.1f * v; }

// ============================================================================
// K1 (MFMA, LDS-staged, TAIL atomics): [A|B] = f @ W'.
// R9 finding (kept): atomics-FIRST starved the block's own f-loads -- split
// degree_pass + pure node ran ~35-42us vs 59.6 combined. R9 cost (fixed here):
// the 5th dispatch costs ~20us of gap, and edge_mlp inexplicably regressed
// 58->81 in the changed environment. R10: degree atomics moved to the TAIL
// of node_transform -- all K1 loads complete before any atomic issues (the
// interference fix, intra-block), tail atomics overlap other blocks' compute,
// and the 4-dispatch / TRM=64 environment edge_mlp was fastest in is restored.
// R4 lesson (permanent): cooperative grid.sync K2/K3 fusion -> 176us. Deleted.
// Layouts (HW-verified per guide): A-frag A[m=lane&15][k=(lane>>4)*8+j];
// B-frag B[k=(lane>>4)*8+j][n=lane&15]; C/D col=lane&15, row=(lane>>4)*4+reg.
// ============================================================================
__global__ void node_transform(
    const float* __restrict__ f, const float* __restrict__ W1,
    const float* __restrict__ b1,
    const int* __restrict__ ind_i, const float* __restrict__ val,
    H16* __restrict__ A, H16* __restrict__ B,
    float* __restrict__ deg, int N, int E)
{
    __shared__ __align__(16) _Float16 tile[TRM * HSTR];   // 17.4 KB

    const int t    = threadIdx.x;
    const int lane = t & 63;
    const int wv   = t >> 6;          // wave 0..3 -> M-subtile wv
    const int n    = lane & 15;       // MFMA matrix-dim index (col)
    const int quad = lane >> 4;       // k-block / row-group selector

    // ---- load W' B-frags once per block: bfr[nt][ks], k = 32*ks + 8*quad + j
    f16x8 bfr[2][4];
#pragma unroll
    for (int nt = 0; nt < 2; ++nt)
#pragma unroll
        for (int ks = 0; ks < 4; ++ks) {
            f16x8 bf;
#pragma unroll
            for (int j = 0; j < 8; ++j) {
                int k = 32 * ks + 8 * quad + j;
                bf[j] = (_Float16)W1[(size_t)(nt * FDIM + k) * L1OUT + n];
            }
            bfr[nt][ks] = bf;
        }
    float b1v = b1[n];                // folded into nt=0 accumulator init

    // ---- stage 64 f-rows as fp16 into padded LDS tile (coalesced) ----
    const int base = blockIdx.x * TRM;
#pragma unroll
    for (int q = 0; q < 4; ++q) {
        int p  = t + 256 * q;         // half8-chunk index 0..1023
        int r  = p >> 4;              // 16 chunks per row
        int c8 = p & 15;              // chunk within row (8 halves)
        float4 lo = make_float4(0.f, 0.f, 0.f, 0.f);
        float4 hi = lo;
        if (base + r < N) {
            const float4* src = reinterpret_cast<const float4*>(
                f + (size_t)(base + r) * FDIM + c8 * 8);
            lo = src[0];
            hi = src[1];
        }
        f16x8 hx;
        hx[0] = (_Float16)lo.x; hx[1] = (_Float16)lo.y;
        hx[2] = (_Float16)lo.z; hx[3] = (_Float16)lo.w;
        hx[4] = (_Float16)hi.x; hx[5] = (_Float16)hi.y;
        hx[6] = (_Float16)hi.z; hx[7] = (_Float16)hi.w;
        *reinterpret_cast<f16x8*>(&tile[r * HSTR + c8 * 8]) = hx;
    }
    __syncthreads();

    // ---- compute: wave wv handles M-subtile wv (16 rows) ----
    {
        const int m0 = wv * 16;
        f32x4 acc0 = { b1v, b1v, b1v, b1v };      // A-cols + b1
        f32x4 acc1 = { 0.f, 0.f, 0.f, 0.f };      // B-cols
#pragma unroll
        for (int ks = 0; ks < 4; ++ks) {
            // A-frag: row m0+n, k = 32*ks + 8*quad .. +7  (one ds_read_b128)
            f16x8 af = *reinterpret_cast<const f16x8*>(
                &tile[(m0 + n) * HSTR + 32 * ks + 8 * quad]);
            acc0 = __builtin_amdgcn_mfma_f32_16x16x32_f16(af, bfr[0][ks], acc0, 0, 0, 0);
            acc1 = __builtin_amdgcn_mfma_f32_16x16x32_f16(af, bfr[1][ks], acc1, 0, 0, 0);
        }
        // epilogue: D col = n, rows = m0 + quad*4 + reg
#pragma unroll
        for (int reg = 0; reg < 4; ++reg) {
            int node = base + m0 + quad * 4 + reg;
            if (node < N) {
                reinterpret_cast<_Float16*>(A + node)[n] = (_Float16)acc0[reg];
                reinterpret_cast<_Float16*>(B + node)[n] = (_Float16)acc1[reg];
            }
        }
    }

    // ---- TAIL: degree atomics (grid-stride, fire-and-forget). Placed after
    // all of this block's loads/MFMA so the coherence round-trips cannot
    // starve them (R9's measured interference mechanism).
    {
        const int gtid = blockIdx.x * 256 + t;
        const int GT   = gridDim.x * 256;
        const int E4   = E >> 2;
        for (int q = gtid; q < E4; q += GT) {
            int e = q << 2;
            int4   ii = *reinterpret_cast<const int4*>(ind_i + e);
            float4 vv = *reinterpret_cast<const float4*>(val + e);
            atomicAdd(&deg[ii.x], fabsf(vv.x));
            atomicAdd(&deg[ii.y], fabsf(vv.y));
            atomicAdd(&deg[ii.z], fabsf(vv.z));
            atomicAdd(&deg[ii.w], fabsf(vv.w));
        }
        if (gtid < (E & 3)) {
            int e = (E & ~3) + gtid;
            atomicAdd(&deg[ind_i[e]], fabsf(val[e]));
        }
    }
}

// ============================================================================
// Shared MLP tail: x[17] -> L2 layer -> collapse -> exp. NO references/structs
// in the hot path (R1 lesson: addressable gather results -> alloca -> 672 MB
// scratch traffic). All indices compile-time; SROA keeps everything in VGPRs.
// ============================================================================
#define MLP_TAIL(X, EXOUT)                                                  \
    {                                                                       \
        float acc[L2DIM];                                                   \
        _Pragma("unroll")                                                   \
        for (int r = 0; r < L2DIM; ++r) acc[r] = b2s[r];                    \
        _Pragma("unroll")                                                   \
        for (int c = 0; c < L2DIM; ++c) {                                   \
            float xc = X[c];                                                \
            const float4* r4 = reinterpret_cast<const float4*>(&w2s[c * 20]); \
            float4 w0 = r4[0], w1v = r4[1], w2v = r4[2], w3 = r4[3];        \
            float  w16 = w2s[c * 20 + 16];                                  \
            acc[0]  += xc * w0.x;  acc[1]  += xc * w0.y;                    \
            acc[2]  += xc * w0.z;  acc[3]  += xc * w0.w;                    \
            acc[4]  += xc * w1v.x; acc[5]  += xc * w1v.y;                   \
            acc[6]  += xc * w1v.z; acc[7]  += xc * w1v.w;                   \
            acc[8]  += xc * w2v.x; acc[9]  += xc * w2v.y;                   \
            acc[10] += xc * w2v.z; acc[11] += xc * w2v.w;                   \
            acc[12] += xc * w3.x;  acc[13] += xc * w3.y;                    \
            acc[14] += xc * w3.z;  acc[15] += xc * w3.w;                    \
            acc[16] += xc * w16;                                            \
        }                                                                   \
        float ev = bc0s;                                                    \
        _Pragma("unroll")                                                   \
        for (int r = 0; r < L2DIM; ++r) ev += lrelu(acc[r]) * wcs[r];       \
        EXOUT = __expf(ev);                                                 \
    }

#define EDGE_X(X, ALO, AHI, BLO, BHI, V, D)                                 \
    _Pragma("unroll")                                                       \
    for (int k = 0; k < 8; ++k) {                                           \
        X[k]     = lrelu((float)ALO[k] + (float)BLO[k]);                    \
        X[k + 8] = lrelu((float)AHI[k] + (float)BHI[k]);                    \
    }                                                                       \
    X[L1OUT] = fabsf(V) / D;

// ============================================================================
// K2: per-edge MLP -> exp -> segment-sum. R2-exact (best measured: 58.2us):
// 256 threads, 2 edges/thread (e, e+E/2), lb(256,4).
// Geometry exhausted (R0/R2/R5/R6/R8: 58-63); R8 refuted dispatch-rate; R7:
// lb(256,8) spills; R5/R6: ILP pins dead. R9's 81us regression under the
// 5-dispatch/TRM-192 environment is what R10's restore tests.
// ============================================================================
__global__ __launch_bounds__(256, 4) void edge_mlp(
    const int* __restrict__ ind, const float* __restrict__ val,
    const H16* __restrict__ A, const H16* __restrict__ B,
    const float* __restrict__ deg,
    const float* __restrict__ W2, const float* __restrict__ b2,
    const float* __restrict__ Wc, const float* __restrict__ bc,
    float* __restrict__ eout, float* __restrict__ ssum, int E)
{
    __shared__ float w2s[L2DIM * 20];   // row c at w2s[c*20], 16B-aligned
    __shared__ float b2s[L2DIM];
    __shared__ float wcs[L2DIM];
    __shared__ float bc0s;

    const int t = threadIdx.x;
    for (int idx = t; idx < L2DIM * L2DIM; idx += 256) {
        int c = idx / L2DIM, r = idx - c * L2DIM;
        w2s[c * 20 + r] = W2[idx];
    }
    if (t < L2DIM) b2s[t] = b2[t];
    if (t < L2DIM) wcs[t] = Wc[t];
    if (t == 0)    bc0s   = bc[0];
    __syncthreads();

    const int E2 = (E + 1) >> 1;          // pair stride
    const int p  = blockIdx.x * 256 + t;
    if (p >= E2) return;

    const int  e0   = p;
    const int  e1   = p + E2;
    const bool has1 = (e1 < E);
    const int  e1s  = has1 ? e1 : e0;     // safe clone address for tail

    // ---- issue the full load pipeline for both edges up front ----
    int i0 = ind[e0];   int j0 = ind[E + e0];
    int i1 = ind[e1s];  int j1 = ind[E + e1s];

    const f16x8* pA0 = reinterpret_cast<const f16x8*>(A + i0);
    const f16x8* pB0 = reinterpret_cast<const f16x8*>(B + j0);
    const f16x8* pA1 = reinterpret_cast<const f16x8*>(A + i1);
    const f16x8* pB1 = reinterpret_cast<const f16x8*>(B + j1);

    f16x8 a0lo = pA0[0], a0hi = pA0[1];   // 2x global_load_dwordx4 each
    f16x8 b0lo = pB0[0], b0hi = pB0[1];
    float v0   = val[e0];
    float d0   = deg[i0];
    f16x8 a1lo = pA1[0], a1hi = pA1[1];
    f16x8 b1lo = pB1[0], b1hi = pB1[1];
    float v1   = val[e1s];
    float d1   = deg[i1];

    // ---- edge 0 ----
    {
        float x[L2DIM];
        EDGE_X(x, a0lo, a0hi, b0lo, b0hi, v0, d0);
        float ex0;
        MLP_TAIL(x, ex0);
        eout[e0] = ex0;
        atomicAdd(&ssum[i0], ex0);
    }

    // ---- edge 1 ----
    if (has1) {
        float x[L2DIM];
        EDGE_X(x, a1lo, a1hi, b1lo, b1hi, v1, d1);
        float ex1;
        MLP_TAIL(x, ex1);
        eout[e1] = ex1;
        atomicAdd(&ssum[i1], ex1);
    }
}

// ============================================================================
// K3: out = ex / s[i], 4 edges/thread vectorized (R2-proven)
// ============================================================================
__global__ void normalize(const int* __restrict__ ind_i, const float* __restrict__ ssum,
                          float* __restrict__ ex, int E) {
    int t = blockIdx.x * blockDim.x + threadIdx.x;
    int e = t * 4;
    if (e + 3 < E) {
        int4   ii = *reinterpret_cast<const int4*>(ind_i + e);
        float4 vv = *reinterpret_cast<const float4*>(ex + e);
        vv.x /= ssum[ii.x];
        vv.y /= ssum[ii.y];
        vv.z /= ssum[ii.z];
        vv.w /= ssum[ii.w];
        *reinterpret_cast<float4*>(ex + e) = vv;
    } else {
        for (; e < E; ++e) ex[e] = ex[e] / ssum[ind_i[e]];
    }
}

extern "C" void kernel_launch(void* const* d_in, const int* in_sizes, int n_in,
                              void* d_out, int out_size, void* d_ws, size_t ws_size,
                              hipStream_t stream) {
    const int*   Jt_ind = (const int*)  d_in[0];   // [2,E]
    const float* Jt_val = (const float*)d_in[1];   // [E]
    const float* f      = (const float*)d_in[2];   // [N,128]
    const float* W1 = (const float*)d_in[4];       // [256,16]
    const float* b1 = (const float*)d_in[5];       // [16]
    const float* W2 = (const float*)d_in[6];       // [17,17]
    const float* b2 = (const float*)d_in[7];       // [17]
    const float* Wc = (const float*)d_in[8];       // [17,1]
    const float* bc = (const float*)d_in[9];       // [1]

    const int E = in_sizes[1];
    const int N = in_sizes[2] / FDIM;
    float* out = (float*)d_out;                    // [E] fp32

    // workspace: deg[N] | ssum[N] (contiguous -> one memset) | A[N] | B[N]
    char* ws = (char*)d_ws;
    float* deg  = (float*)ws;  ws += (size_t)N * sizeof(float);
    float* ssum = (float*)ws;  ws += (size_t)N * sizeof(float);
    H16*   A    = (H16*)ws;    ws += (size_t)N * sizeof(H16);
    H16*   Bm   = (H16*)ws;    ws += (size_t)N * sizeof(H16);

    const int B256 = 256;
    const int nblk = (N + TRM - 1) / TRM;                   // 1563 node tiles
    const int E2   = (E + 1) / 2;                           // edge pairs
    const int eblk = (E2 + B256 - 1) / B256;                // 1563 blocks (R2)
    const int qblk = ((E + 3) / 4 + B256 - 1) / B256;       // 782 blocks

    hipMemsetAsync(deg, 0, 2 * (size_t)N * sizeof(float), stream);
    node_transform<<<nblk, B256, 0, stream>>>(f, W1, b1, Jt_ind, Jt_val,
                                              A, Bm, deg, N, E);
    edge_mlp      <<<eblk, B256, 0, stream>>>(Jt_ind, Jt_val, A, Bm, deg,
                                              W2, b2, Wc, bc, out, ssum, E);
    normalize     <<<qblk, B256, 0, stream>>>(Jt_ind, ssum, out, E);
}